// Round 3
// baseline (445.276 us; speedup 1.0000x reference)
//
#include <hip/hip_runtime.h>

#define HID 10
#define INP 64
#define STEPS 512

typedef __attribute__((ext_vector_type(8))) short v8s;   // 8 x bf16 (4 VGPRs)
typedef __attribute__((ext_vector_type(4))) float v4f;
typedef __attribute__((ext_vector_type(2))) float v2f;
typedef __attribute__((ext_vector_type(4))) int   v4i;

#define MFMA(A, Bf, C) __builtin_amdgcn_mfma_f32_16x16x32_bf16((A), (Bf), (C), 0, 0, 0)

static __device__ __forceinline__ v8s frag_from(unsigned d0, unsigned d1, unsigned d2, unsigned d3) {
    v4i t; t.x = (int)d0; t.y = (int)d1; t.z = (int)d2; t.w = (int)d3;
    return __builtin_bit_cast(v8s, t);
}
static __device__ __forceinline__ unsigned pkhi(float a, float b) {
    return (__float_as_uint(a) >> 16) | (__float_as_uint(b) & 0xffff0000u);
}
static __device__ __forceinline__ float hif(float a) {
    return __uint_as_float(__float_as_uint(a) & 0xffff0000u);
}
// 8 floats -> hi frag (bf16-trunc) + lo frag (bf16-trunc of residual). Combined ~2^-16 rel.
static __device__ __forceinline__ void split8(const float* v, v8s& hi, v8s& lo) {
    hi = frag_from(pkhi(v[0], v[1]), pkhi(v[2], v[3]), pkhi(v[4], v[5]), pkhi(v[6], v[7]));
    float l0 = v[0] - hif(v[0]), l1 = v[1] - hif(v[1]);
    float l2 = v[2] - hif(v[2]), l3 = v[3] - hif(v[3]);
    float l4 = v[4] - hif(v[4]), l5 = v[5] - hif(v[5]);
    float l6 = v[6] - hif(v[6]), l7 = v[7] - hif(v[7]);
    lo = frag_from(pkhi(l0, l1), pkhi(l2, l3), pkhi(l4, l5), pkhi(l6, l7));
}

static __device__ __forceinline__ unsigned bpermu(int addr, unsigned x) {
    return (unsigned)__builtin_amdgcn_ds_bpermute(addr, (int)x);
}

// h in C-layout (lane holds h[q*4+i][r15]) -> B-frags, split bf16, via PACKED bpermute.
// Pack in C-layout (4 hi/lo words), then 8 bpermutes of packed words form the frags directly.
// B-frag word w of target (q,r15) = packed word (w&1) of source lane ((2q+(w>>1))*16+r15)&63.
// Garbage pulled for q>=2 (k=16..31) is finite and multiplied by zero weight rows -> harmless.
static __device__ __forceinline__ void pack_bperm(const v4f& hC, int a0, int a1, v8s& hi, v8s& lo) {
    unsigned whi0 = pkhi(hC[0], hC[1]);
    unsigned whi1 = pkhi(hC[2], hC[3]);
    float l0 = hC[0] - hif(hC[0]), l1 = hC[1] - hif(hC[1]);
    float l2 = hC[2] - hif(hC[2]), l3 = hC[3] - hif(hC[3]);
    unsigned wlo0 = pkhi(l0, l1), wlo1 = pkhi(l2, l3);
    hi = frag_from(bpermu(a0, whi0), bpermu(a0, whi1), bpermu(a1, whi0), bpermu(a1, whi1));
    lo = frag_from(bpermu(a0, wlo0), bpermu(a0, wlo1), bpermu(a1, wlo0), bpermu(a1, wlo1));
}

// depth-1 split-bf16 matmul stage: 3 independent MFMAs + 2 VALU adds
static __device__ __forceinline__ v4f mm3(v8s Ah, v8s Al, v8s Bh, v8s Bl, v4f bias) {
    v4f z = {0.f, 0.f, 0.f, 0.f};
    v4f P1 = MFMA(Ah, Bh, bias);
    v4f P2 = MFMA(Al, Bh, z);
    v4f P3 = MFMA(Ah, Bl, z);
    return (P1 + P2) + P3;
}

// CrN/CzN are pre-negated & log2e-scaled; Cni/Cnh are 2*log2e-scaled.
static __device__ __forceinline__ void gate_update(const v4f& CrN, const v4f& CzN,
                                                   const v4f& Cni, const v4f& Cnh, v4f& hC) {
    #pragma unroll
    for (int i = 0; i < 4; ++i) {
        float r = __builtin_amdgcn_rcpf(1.f + __builtin_amdgcn_exp2f(CrN[i]));
        float z = __builtin_amdgcn_rcpf(1.f + __builtin_amdgcn_exp2f(CzN[i]));
        float y = Cni[i] + r * Cnh[i];
        float n = 1.f - 2.f * __builtin_amdgcn_rcpf(1.f + __builtin_amdgcn_exp2f(y));
        hC[i] = n + z * (hC[i] - n);
    }
}

// Fused recurrence (x-path folded into gate weights, see round-2 derivation).
// Per step: 12 gate MFMAs (depth 1) -> gate VALU -> pack+bperm -> [o-path + LDS stage, off path].
// Output staged in LDS (reversed step order), flushed every 64 steps as coalesced dwordx4.
__global__ __launch_bounds__(64, 1) void gru_decoder_kernel(
    const float* __restrict__ hidden, const float* __restrict__ w_ih,
    const float* __restrict__ w_hh, const float* __restrict__ b_ih,
    const float* __restrict__ b_hh, const float* __restrict__ l1_w,
    const float* __restrict__ l1_b, const float* __restrict__ l2_w,
    const float* __restrict__ l2_b, float* __restrict__ out)
{
    __shared__ float sWx[640];        // (l2_w @ l1_w), 64x10
    __shared__ float sbx[64];         // l2_w @ l1_b + l2_b
    __shared__ float sWgi[300];       // w_ih @ Wx, 30x10
    __shared__ float sbgi[30];        // b_ih + w_ih @ bx
    __shared__ float sout[16 * 644];  // [batch][64 steps x 10 feat, pad to 644]

    const int lane = threadIdx.x;
    const int r15  = lane & 15;
    const int q    = lane >> 4;

    // ---- preamble: fused weights (fp32, cooperative) ----
    for (int e = lane; e < 640; e += 64) {
        int i = e / 10, j = e - i * 10;
        float acc = 0.f;
        #pragma unroll
        for (int k = 0; k < 10; ++k) acc += l2_w[i * 10 + k] * l1_w[k * 10 + j];
        sWx[e] = acc;
    }
    {
        float acc = l2_b[lane];
        #pragma unroll
        for (int k = 0; k < 10; ++k) acc += l2_w[lane * 10 + k] * l1_b[k];
        sbx[lane] = acc;
    }
    __syncthreads();
    for (int e = lane; e < 300; e += 64) {
        int m = e / 10, j = e - m * 10;
        float acc = 0.f;
        for (int k = 0; k < 64; ++k) acc += w_ih[m * 64 + k] * sWx[k * 10 + j];
        sWgi[e] = acc;
    }
    if (lane < 30) {
        float acc = b_ih[lane];
        for (int k = 0; k < 64; ++k) acc += w_ih[lane * 64 + k] * sbx[k];
        sbgi[lane] = acc;
    }
    __syncthreads();

    const float LOG2E = 1.4426950408889634f;
    const float S2    = 2.f * LOG2E;

    // ---- constant A-frags (m=r15, k=q*8+j); r/z negated+log2e, n 2*log2e prefolded ----
    v8s Wrh, Wrl, Wzh, Wzl, Wnih, Wnil, Wnhh, Wnhl, L1h, L1l, Prh, Prl, Pzh, Pzl;
    {
        float vr[8], vz[8], vni[8], vnh[8], vl1[8], vpr[8], vpz[8];
        #pragma unroll
        for (int j = 0; j < 8; ++j) {
            int k = q * 8 + j;
            float wpr = 0.f, wpz = 0.f, wnh = 0.f, wr = 0.f, wz = 0.f, wni = 0.f, wl1 = 0.f;
            if (r15 < 10 && k < 10) {
                wpr = w_hh[r15 * 10 + k];
                wpz = w_hh[(10 + r15) * 10 + k];
                wnh = w_hh[(20 + r15) * 10 + k];
                wr  = sWgi[r15 * 10 + k] + wpr;
                wz  = sWgi[(10 + r15) * 10 + k] + wpz;
                wni = sWgi[(20 + r15) * 10 + k];
                wl1 = l1_w[r15 * 10 + k];
            }
            vr[j] = -wr * LOG2E;  vz[j] = -wz * LOG2E;
            vni[j] = wni * S2;    vnh[j] = wnh * S2;
            vl1[j] = wl1;
            vpr[j] = -wpr * LOG2E; vpz[j] = -wpz * LOG2E;
        }
        split8(vr, Wrh, Wrl); split8(vz, Wzh, Wzl);
        split8(vni, Wnih, Wnil); split8(vnh, Wnhh, Wnhl);
        split8(vl1, L1h, L1l);
        split8(vpr, Prh, Prl); split8(vpz, Pzh, Pzl);
    }

    // ---- bias frags (C layout: f=q*4+i) ----
    v4f Br, Bz, Bni, Bnh, Bo, Br0, Bz0, Bni0;
    #pragma unroll
    for (int i = 0; i < 4; ++i) {
        int f = q * 4 + i;
        bool ok = f < 10;
        Br[i]   = ok ? -(sbgi[f] + b_hh[f]) * LOG2E : 0.f;
        Bz[i]   = ok ? -(sbgi[10 + f] + b_hh[10 + f]) * LOG2E : 0.f;
        Bni[i]  = ok ? sbgi[20 + f] * S2 : 0.f;
        Bnh[i]  = ok ? b_hh[20 + f] * S2 : 0.f;
        Bo[i]   = ok ? l1_b[f] : 0.f;
        Br0[i]  = ok ? -(b_ih[f] + b_hh[f]) * LOG2E : 0.f;
        Bz0[i]  = ok ? -(b_ih[10 + f] + b_hh[10 + f]) * LOG2E : 0.f;
        Bni0[i] = ok ? b_ih[20 + f] * S2 : 0.f;
    }

    // bpermute source-lane byte addresses (constant per lane)
    const int a0 = (((2 * q + 0) * 16 + r15) & 63) * 4;
    const int a1 = (((2 * q + 1) * 16 + r15) & 63) * 4;

    // ---- initial h (rows >= 10 are 0 and stay 0 exactly) ----
    v4f hC;
    #pragma unroll
    for (int i = 0; i < 4; ++i) {
        int f = q * 4 + i;
        hC[i] = (f < 10) ? hidden[((size_t)blockIdx.x * 16 + r15) * HID + f] : 0.f;
    }
    v8s hBh, hBl;
    pack_bperm(hC, a0, a1, hBh, hBl);

    float* const outblk = out + (size_t)blockIdx.x * 16 * (STEPS * HID);

    #pragma unroll 1
    for (int t = 0; t < STEPS; ++t) {
        v4f CrN, CzN, Cni, Cnh;
        if (t == 0) {   // peeled: gi = b_ih only (x_0 = 0); wave-uniform branch, once
            CrN = mm3(Prh, Prl, hBh, hBl, Br0);
            CzN = mm3(Pzh, Pzl, hBh, hBl, Bz0);
            Cni = Bni0;
            Cnh = mm3(Wnhh, Wnhl, hBh, hBl, Bnh);
        } else {
            CrN = mm3(Wrh, Wrl, hBh, hBl, Br);
            CzN = mm3(Wzh, Wzl, hBh, hBl, Bz);
            Cni = mm3(Wnih, Wnil, hBh, hBl, Bni);
            Cnh = mm3(Wnhh, Wnhl, hBh, hBl, Bnh);
        }
        gate_update(CrN, CzN, Cni, Cnh, hC);
        pack_bperm(hC, a0, a1, hBh, hBl);        // h_{t+1} -> B-frags (critical path)

        // ---- o-path + LDS staging (off the recurrence path) ----
        v4f Co = MFMA(L1h, hBh, Bo);
        Co = MFMA(L1l, hBh, Co);
        {
            int p = 63 - (t & 63);               // reversed position within 64-step block
            float* so = &sout[r15 * 644 + p * 10 + q * 4];
            if (q < 3) { v2f s0; s0.x = Co[0]; s0.y = Co[1]; *reinterpret_cast<v2f*>(so) = s0; }
            if (q < 2) { v2f s1; s1.x = Co[2]; s1.y = Co[3]; *reinterpret_cast<v2f*>(so + 2) = s1; }
        }

        // ---- flush every 64 steps: coalesced dwordx4, reversed region is contiguous ----
        if ((t & 63) == 63) {
            const int base = (511 - t) * 10;     // output float offset of this 64-step block
            float* gout = outblk + base;
            #pragma unroll 8
            for (int i = 0; i < 40; ++i) {
                unsigned idx = (unsigned)(i * 64 + lane);   // 0..2559
                unsigned b = idx / 160u;                    // batch sub-index
                unsigned c = idx - b * 160u;                // dwordx4 chunk within batch
                v4f val = *reinterpret_cast<const v4f*>(&sout[b * 644 + c * 4]);
                *reinterpret_cast<v4f*>(gout + (size_t)b * (STEPS * HID) + c * 4) = val;
            }
        }
    }
}

extern "C" void kernel_launch(void* const* d_in, const int* in_sizes, int n_in,
                              void* d_out, int out_size, void* d_ws, size_t ws_size,
                              hipStream_t stream) {
    (void)in_sizes; (void)n_in; (void)d_ws; (void)ws_size; (void)out_size;
    dim3 grid(512), block(64);   // 8192 batch / 16 per wave-tile
    gru_decoder_kernel<<<grid, block, 0, stream>>>(
        (const float*)d_in[0], (const float*)d_in[1], (const float*)d_in[2],
        (const float*)d_in[3], (const float*)d_in[4], (const float*)d_in[5],
        (const float*)d_in[6], (const float*)d_in[7], (const float*)d_in[8],
        (float*)d_out);
}

// Round 4
// 406.129 us; speedup vs baseline: 1.0964x; 1.0964x over previous
//
#include <hip/hip_runtime.h>

#define HID 10
#define INP 64
#define STEPS 512

typedef __attribute__((ext_vector_type(8))) short v8s;   // 8 x bf16 (4 VGPRs)
typedef __attribute__((ext_vector_type(4))) float v4f;
typedef __attribute__((ext_vector_type(2))) float v2f;
typedef __attribute__((ext_vector_type(4))) int   v4i;

#define MFMA(A, Bf, C) __builtin_amdgcn_mfma_f32_16x16x32_bf16((A), (Bf), (C), 0, 0, 0)

static __device__ __forceinline__ v8s frag_from(unsigned d0, unsigned d1, unsigned d2, unsigned d3) {
    v4i t; t.x = (int)d0; t.y = (int)d1; t.z = (int)d2; t.w = (int)d3;
    return __builtin_bit_cast(v8s, t);
}
static __device__ __forceinline__ unsigned pkhi(float a, float b) {
    return (__float_as_uint(a) >> 16) | (__float_as_uint(b) & 0xffff0000u);
}
static __device__ __forceinline__ float hif(float a) {
    return __uint_as_float(__float_as_uint(a) & 0xffff0000u);
}
// 8 floats -> hi frag (bf16-trunc) + lo frag (bf16-trunc of residual). Combined ~2^-16 rel.
static __device__ __forceinline__ void split8(const float* v, v8s& hi, v8s& lo) {
    hi = frag_from(pkhi(v[0], v[1]), pkhi(v[2], v[3]), pkhi(v[4], v[5]), pkhi(v[6], v[7]));
    float l0 = v[0] - hif(v[0]), l1 = v[1] - hif(v[1]);
    float l2 = v[2] - hif(v[2]), l3 = v[3] - hif(v[3]);
    float l4 = v[4] - hif(v[4]), l5 = v[5] - hif(v[5]);
    float l6 = v[6] - hif(v[6]), l7 = v[7] - hif(v[7]);
    lo = frag_from(pkhi(l0, l1), pkhi(l2, l3), pkhi(l4, l5), pkhi(l6, l7));
}

static __device__ __forceinline__ unsigned bpermu(int addr, unsigned x) {
    return (unsigned)__builtin_amdgcn_ds_bpermute(addr, (int)x);
}

// h in C-layout (lane holds h[q*4+i][r15]) -> B-frags via PACKED bpermute (8 ds_bpermute).
// Garbage pulled for q>=2 (k=16..31) is finite and hits zero weight rows -> harmless.
static __device__ __forceinline__ void pack_bperm(const v4f& hC, int a0, int a1, v8s& hi, v8s& lo) {
    unsigned whi0 = pkhi(hC[0], hC[1]);
    unsigned whi1 = pkhi(hC[2], hC[3]);
    float l0 = hC[0] - hif(hC[0]), l1 = hC[1] - hif(hC[1]);
    float l2 = hC[2] - hif(hC[2]), l3 = hC[3] - hif(hC[3]);
    unsigned wlo0 = pkhi(l0, l1), wlo1 = pkhi(l2, l3);
    hi = frag_from(bpermu(a0, whi0), bpermu(a0, whi1), bpermu(a1, whi0), bpermu(a1, whi1));
    lo = frag_from(bpermu(a0, wlo0), bpermu(a0, wlo1), bpermu(a1, wlo0), bpermu(a1, wlo1));
}

// depth-1 split-bf16 matmul stage: 3 independent MFMAs + vector adds
static __device__ __forceinline__ v4f mm3(v8s Ah, v8s Al, v8s Bh, v8s Bl, v4f bias) {
    v4f z = {0.f, 0.f, 0.f, 0.f};
    v4f P1 = MFMA(Ah, Bh, bias);
    v4f P2 = MFMA(Al, Bh, z);
    v4f P3 = MFMA(Ah, Bl, z);
    return (P1 + P2) + P3;
}

// CrN/CzN pre-negated & log2e-scaled; Cni/Cnh 2*log2e-scaled.
static __device__ __forceinline__ void gate_update(const v4f& CrN, const v4f& CzN,
                                                   const v4f& Cni, const v4f& Cnh, v4f& hC) {
    #pragma unroll
    for (int i = 0; i < 4; ++i) {
        float r = __builtin_amdgcn_rcpf(1.f + __builtin_amdgcn_exp2f(CrN[i]));
        float z = __builtin_amdgcn_rcpf(1.f + __builtin_amdgcn_exp2f(CzN[i]));
        float y = Cni[i] + r * Cnh[i];
        float n = 1.f - 2.f * __builtin_amdgcn_rcpf(1.f + __builtin_amdgcn_exp2f(y));
        hC[i] = n + z * (hC[i] - n);
    }
}

// Fused recurrence (x-path folded into gate weights, round-2 derivation).
// Per step: 12 gate MFMAs (depth 1) -> gate VALU -> pack+bperm -> o-path + direct stores.
// Time loop unrolled x2 so store-register reuse (vmcnt) is ~2 steps away and the o-path
// of step t shares a scheduling region with step t+1's gate MFMAs.
__global__ __launch_bounds__(64, 1) void gru_decoder_kernel(
    const float* __restrict__ hidden, const float* __restrict__ w_ih,
    const float* __restrict__ w_hh, const float* __restrict__ b_ih,
    const float* __restrict__ b_hh, const float* __restrict__ l1_w,
    const float* __restrict__ l1_b, const float* __restrict__ l2_w,
    const float* __restrict__ l2_b, float* __restrict__ out)
{
    __shared__ float sWx[640];   // (l2_w @ l1_w), 64x10
    __shared__ float sbx[64];    // l2_w @ l1_b + l2_b
    __shared__ float sWgi[300];  // w_ih @ Wx, 30x10
    __shared__ float sbgi[30];   // b_ih + w_ih @ bx

    const int lane = threadIdx.x;
    const int r15  = lane & 15;
    const int q    = lane >> 4;

    // ---- preamble: fused weights (fp32, cooperative) ----
    for (int e = lane; e < 640; e += 64) {
        int i = e / 10, j = e - i * 10;
        float acc = 0.f;
        #pragma unroll
        for (int k = 0; k < 10; ++k) acc += l2_w[i * 10 + k] * l1_w[k * 10 + j];
        sWx[e] = acc;
    }
    {
        float acc = l2_b[lane];
        #pragma unroll
        for (int k = 0; k < 10; ++k) acc += l2_w[lane * 10 + k] * l1_b[k];
        sbx[lane] = acc;
    }
    __syncthreads();
    for (int e = lane; e < 300; e += 64) {
        int m = e / 10, j = e - m * 10;
        float acc = 0.f;
        for (int k = 0; k < 64; ++k) acc += w_ih[m * 64 + k] * sWx[k * 10 + j];
        sWgi[e] = acc;
    }
    if (lane < 30) {
        float acc = b_ih[lane];
        for (int k = 0; k < 64; ++k) acc += w_ih[lane * 64 + k] * sbx[k];
        sbgi[lane] = acc;
    }
    __syncthreads();

    const float LOG2E = 1.4426950408889634f;
    const float S2    = 2.f * LOG2E;

    // ---- constant A-frags (m=r15, k=q*8+j); r/z negated+log2e, n 2*log2e prefolded ----
    v8s Wrh, Wrl, Wzh, Wzl, Wnih, Wnil, Wnhh, Wnhl, L1h, L1l, Prh, Prl, Pzh, Pzl;
    {
        float vr[8], vz[8], vni[8], vnh[8], vl1[8], vpr[8], vpz[8];
        #pragma unroll
        for (int j = 0; j < 8; ++j) {
            int k = q * 8 + j;
            float wpr = 0.f, wpz = 0.f, wnh = 0.f, wr = 0.f, wz = 0.f, wni = 0.f, wl1 = 0.f;
            if (r15 < 10 && k < 10) {
                wpr = w_hh[r15 * 10 + k];
                wpz = w_hh[(10 + r15) * 10 + k];
                wnh = w_hh[(20 + r15) * 10 + k];
                wr  = sWgi[r15 * 10 + k] + wpr;
                wz  = sWgi[(10 + r15) * 10 + k] + wpz;
                wni = sWgi[(20 + r15) * 10 + k];
                wl1 = l1_w[r15 * 10 + k];
            }
            vr[j] = -wr * LOG2E;  vz[j] = -wz * LOG2E;
            vni[j] = wni * S2;    vnh[j] = wnh * S2;
            vl1[j] = wl1;
            vpr[j] = -wpr * LOG2E; vpz[j] = -wpz * LOG2E;
        }
        split8(vr, Wrh, Wrl); split8(vz, Wzh, Wzl);
        split8(vni, Wnih, Wnil); split8(vnh, Wnhh, Wnhl);
        split8(vl1, L1h, L1l);
        split8(vpr, Prh, Prl); split8(vpz, Pzh, Pzl);
    }

    // ---- bias frags (C layout: f=q*4+i) ----
    v4f Br, Bz, Bni, Bnh, Bo, Br0, Bz0, Bni0;
    #pragma unroll
    for (int i = 0; i < 4; ++i) {
        int f = q * 4 + i;
        bool ok = f < 10;
        Br[i]   = ok ? -(sbgi[f] + b_hh[f]) * LOG2E : 0.f;
        Bz[i]   = ok ? -(sbgi[10 + f] + b_hh[10 + f]) * LOG2E : 0.f;
        Bni[i]  = ok ? sbgi[20 + f] * S2 : 0.f;
        Bnh[i]  = ok ? b_hh[20 + f] * S2 : 0.f;
        Bo[i]   = ok ? l1_b[f] : 0.f;
        Br0[i]  = ok ? -(b_ih[f] + b_hh[f]) * LOG2E : 0.f;
        Bz0[i]  = ok ? -(b_ih[10 + f] + b_hh[10 + f]) * LOG2E : 0.f;
        Bni0[i] = ok ? b_ih[20 + f] * S2 : 0.f;
    }

    // bpermute source-lane byte addresses (constant per lane)
    const int a0 = (((2 * q + 0) * 16 + r15) & 63) * 4;
    const int a1 = (((2 * q + 1) * 16 + r15) & 63) * 4;

    // ---- initial h (rows >= 10 are 0 and stay 0 exactly) ----
    v4f hC;
    #pragma unroll
    for (int i = 0; i < 4; ++i) {
        int f = q * 4 + i;
        hC[i] = (f < 10) ? hidden[((size_t)blockIdx.x * 16 + r15) * HID + f] : 0.f;
    }
    v8s hBh, hBl;
    pack_bperm(hC, a0, a1, hBh, hBl);

    // per-lane output pointer: batch r15, feature base q*4, step slot (511-t)
    float* poq = out + ((size_t)blockIdx.x * 16 + r15) * (STEPS * HID)
                     + (size_t)(STEPS - 1) * HID + q * 4;

    // one full step: gates -> update -> bperm -> o-path -> masked v2f stores
    auto STEP = [&]() {
        v4f CrN = mm3(Wrh, Wrl, hBh, hBl, Br);
        v4f CzN = mm3(Wzh, Wzl, hBh, hBl, Bz);
        v4f Cni = mm3(Wnih, Wnil, hBh, hBl, Bni);
        v4f Cnh = mm3(Wnhh, Wnhl, hBh, hBl, Bnh);
        gate_update(CrN, CzN, Cni, Cnh, hC);
        pack_bperm(hC, a0, a1, hBh, hBl);
        v4f Co = MFMA(L1h, hBh, Bo);
        Co = MFMA(L1l, hBh, Co);
        if (q < 3) { v2f s0; s0.x = Co[0]; s0.y = Co[1]; *reinterpret_cast<v2f*>(poq) = s0; }
        if (q < 2) { v2f s1; s1.x = Co[2]; s1.y = Co[3]; *reinterpret_cast<v2f*>(poq + 2) = s1; }
        poq -= HID;
    };

    // ---- t = 0 peeled (gi = b_ih only; x_0 = 0) ----
    {
        v4f CrN = mm3(Prh, Prl, hBh, hBl, Br0);
        v4f CzN = mm3(Pzh, Pzl, hBh, hBl, Bz0);
        v4f Cnh = mm3(Wnhh, Wnhl, hBh, hBl, Bnh);
        gate_update(CrN, CzN, Bni0, Cnh, hC);
        pack_bperm(hC, a0, a1, hBh, hBl);
        v4f Co = MFMA(L1h, hBh, Bo);
        Co = MFMA(L1l, hBh, Co);
        if (q < 3) { v2f s0; s0.x = Co[0]; s0.y = Co[1]; *reinterpret_cast<v2f*>(poq) = s0; }
        if (q < 2) { v2f s1; s1.x = Co[2]; s1.y = Co[3]; *reinterpret_cast<v2f*>(poq + 2) = s1; }
        poq -= HID;
    }

    // ---- t = 1 .. 510 as 255 unrolled pairs, then t = 511 tail ----
    #pragma unroll 1
    for (int tp = 0; tp < 255; ++tp) {
        STEP();
        STEP();
    }
    STEP();
}

extern "C" void kernel_launch(void* const* d_in, const int* in_sizes, int n_in,
                              void* d_out, int out_size, void* d_ws, size_t ws_size,
                              hipStream_t stream) {
    (void)in_sizes; (void)n_in; (void)d_ws; (void)ws_size; (void)out_size;
    dim3 grid(512), block(64);   // 8192 batch / 16 per wave-tile
    gru_decoder_kernel<<<grid, block, 0, stream>>>(
        (const float*)d_in[0], (const float*)d_in[1], (const float*)d_in[2],
        (const float*)d_in[3], (const float*)d_in[4], (const float*)d_in[5],
        (const float*)d_in[6], (const float*)d_in[7], (const float*)d_in[8],
        (float*)d_out);
}

// Round 5
// 360.149 us; speedup vs baseline: 1.2364x; 1.1277x over previous
//
#include <hip/hip_runtime.h>

#define HID 10
#define STEPS 512

typedef __attribute__((ext_vector_type(2))) float v2f;

// quad_perm broadcast: every lane in a quad reads quad-lane S
template<int S>
static __device__ __forceinline__ float qb(float v) {
    return __int_as_float(__builtin_amdgcn_update_dpp(
        0, __float_as_int(v), S * 0x55, 0xF, 0xF, true));
}

// Lane-parallel fused GRU decoder (no MFMA, no LDS in the steady-state loop).
//   batch  = blockIdx*16 + (lane>>2)   (16 batches per wave, 512 waves)
//   sub    = lane&3: owns features f = sub*3 + {0,1,2} (f>=10 are zero-padded)
// Fused recurrence (x-path folded, round-2 derivation):
//   gates = (Wgi + Whh) @ h + biases for r,z; ni from Wgi; nh from Whh.
// Per step: 12 gate dots (len 10, float2/pk-fma) -> 18 trans -> h update ->
//   10 quad_perm DPP broadcasts (h hand-off) -> 3 o-dots -> reversed stores.
__global__ __launch_bounds__(64, 1) void gru_decoder_kernel(
    const float* __restrict__ hidden, const float* __restrict__ w_ih,
    const float* __restrict__ w_hh, const float* __restrict__ b_ih,
    const float* __restrict__ b_hh, const float* __restrict__ l1_w,
    const float* __restrict__ l1_b, const float* __restrict__ l2_w,
    const float* __restrict__ l2_b, float* __restrict__ out)
{
    __shared__ float sWx[640];   // l2_w @ l1_w (64x10)
    __shared__ float sbx[64];    // l2_w @ l1_b + l2_b
    __shared__ float sWgi[300];  // w_ih @ Wx (30x10)
    __shared__ float sbgi[30];   // b_ih + w_ih @ bx
    __shared__ float sWhh[300];  // w_hh copy (for t=0 peel)

    const int lane = threadIdx.x;
    const int sub  = lane & 3;
    const int b    = blockIdx.x * 16 + (lane >> 2);

    // ---- preamble: fused weights (fp32, cooperative) ----
    for (int e = lane; e < 640; e += 64) {
        int i = e / 10, j = e - i * 10;
        float acc = 0.f;
        #pragma unroll
        for (int k = 0; k < 10; ++k) acc += l2_w[i * 10 + k] * l1_w[k * 10 + j];
        sWx[e] = acc;
    }
    {
        float acc = l2_b[lane];
        #pragma unroll
        for (int k = 0; k < 10; ++k) acc += l2_w[lane * 10 + k] * l1_b[k];
        sbx[lane] = acc;
    }
    for (int e = lane; e < 300; e += 64) sWhh[e] = w_hh[e];
    __syncthreads();
    for (int e = lane; e < 300; e += 64) {
        int m = e / 10, j = e - m * 10;
        float acc = 0.f;
        for (int k = 0; k < 64; ++k) acc += w_ih[m * 64 + k] * sWx[k * 10 + j];
        sWgi[e] = acc;
    }
    if (lane < 30) {
        float acc = b_ih[lane];
        for (int k = 0; k < 64; ++k) acc += w_ih[lane * 64 + k] * sbx[k];
        sbgi[lane] = acc;
    }
    __syncthreads();

    const float LOG2E = 1.4426950408889634f;
    const float S2    = 2.f * LOG2E;

    // ---- per-lane weights in VGPRs (rows f = sub*3+j; f>=10 zero) ----
    v2f wr2[3][5], wz2[3][5], wni2[3][5], wnh2[3][5], wo2[3][5];
    float br[3], bz[3], bni[3], bnh[3], bo[3], bni0[3], br0[3], bz0[3];
    #pragma unroll
    for (int j = 0; j < 3; ++j) {
        const int f = sub * 3 + j;
        const bool ok = (f < 10);
        #pragma unroll
        for (int i = 0; i < 5; ++i) {
            int k0 = 2 * i, k1 = 2 * i + 1;
            v2f zz = {0.f, 0.f};
            if (ok) {
                wr2[j][i] = v2f{-(sWgi[f * 10 + k0] + sWhh[f * 10 + k0]) * LOG2E,
                                -(sWgi[f * 10 + k1] + sWhh[f * 10 + k1]) * LOG2E};
                wz2[j][i] = v2f{-(sWgi[(10 + f) * 10 + k0] + sWhh[(10 + f) * 10 + k0]) * LOG2E,
                                -(sWgi[(10 + f) * 10 + k1] + sWhh[(10 + f) * 10 + k1]) * LOG2E};
                wni2[j][i] = v2f{sWgi[(20 + f) * 10 + k0] * S2, sWgi[(20 + f) * 10 + k1] * S2};
                wnh2[j][i] = v2f{sWhh[(20 + f) * 10 + k0] * S2, sWhh[(20 + f) * 10 + k1] * S2};
                wo2[j][i]  = v2f{l1_w[f * 10 + k0], l1_w[f * 10 + k1]};
            } else {
                wr2[j][i] = zz; wz2[j][i] = zz; wni2[j][i] = zz; wnh2[j][i] = zz; wo2[j][i] = zz;
            }
        }
        br[j]   = ok ? -(sbgi[f] + b_hh[f]) * LOG2E : 0.f;
        bz[j]   = ok ? -(sbgi[10 + f] + b_hh[10 + f]) * LOG2E : 0.f;
        bni[j]  = ok ? sbgi[20 + f] * S2 : 0.f;
        bnh[j]  = ok ? b_hh[20 + f] * S2 : 0.f;
        bo[j]   = ok ? l1_b[f] : 0.f;
        br0[j]  = ok ? -(b_ih[f] + b_hh[f]) * LOG2E : 0.f;
        bz0[j]  = ok ? -(b_ih[10 + f] + b_hh[10 + f]) * LOG2E : 0.f;
        bni0[j] = ok ? b_ih[20 + f] * S2 : 0.f;
    }

    // ---- initial h: my features ----
    float hold[3];
    #pragma unroll
    for (int j = 0; j < 3; ++j) {
        const int f = sub * 3 + j;
        hold[j] = (f < 10) ? hidden[(size_t)b * HID + f] : 0.f;
    }

    // gather helper output
    float ha[10];
    v2f h2[5];
    #define GATHER()                                                     \
        ha[0] = qb<0>(hold[0]); ha[1] = qb<0>(hold[1]); ha[2] = qb<0>(hold[2]); \
        ha[3] = qb<1>(hold[0]); ha[4] = qb<1>(hold[1]); ha[5] = qb<1>(hold[2]); \
        ha[6] = qb<2>(hold[0]); ha[7] = qb<2>(hold[1]); ha[8] = qb<2>(hold[2]); \
        ha[9] = qb<3>(hold[0]);                                          \
        h2[0] = v2f{ha[0], ha[1]}; h2[1] = v2f{ha[2], ha[3]};            \
        h2[2] = v2f{ha[4], ha[5]}; h2[3] = v2f{ha[6], ha[7]};            \
        h2[4] = v2f{ha[8], ha[9]};

    GATHER();

    float* pb = out + (size_t)b * (STEPS * HID) + (size_t)(STEPS - 1) * HID + sub * 3;

    // o-path + store (uses freshly gathered h2)
    #define O_AND_STORE()                                                \
        {                                                                \
            float o0, o1, o2;                                            \
            {                                                            \
                v2f a0 = {0.f, 0.f}, a1 = {0.f, 0.f}, a2 = {0.f, 0.f};   \
                _Pragma("unroll")                                        \
                for (int i = 0; i < 5; ++i) {                            \
                    a0 += wo2[0][i] * h2[i];                             \
                    a1 += wo2[1][i] * h2[i];                             \
                    a2 += wo2[2][i] * h2[i];                             \
                }                                                        \
                o0 = a0.x + a0.y + bo[0];                                \
                o1 = a1.x + a1.y + bo[1];                                \
                o2 = a2.x + a2.y + bo[2];                                \
            }                                                            \
            if (sub < 3) {                                               \
                v2f s; s.x = o0; s.y = o1;                               \
                *reinterpret_cast<v2f*>(pb) = s;                         \
                pb[2] = o2;                                              \
            } else {                                                     \
                pb[0] = o0;                                              \
            }                                                            \
            pb -= HID;                                                   \
        }

    // ---- t = 0 peeled: gi = b_ih only (x_0 = 0); r/z dots from LDS w_hh ----
    {
        #pragma unroll
        for (int j = 0; j < 3; ++j) {
            const int f = sub * 3 + j;
            float pr = 0.f, pz = 0.f;
            if (f < 10) {
                #pragma unroll
                for (int k = 0; k < 10; ++k) {
                    pr += sWhh[f * 10 + k] * ha[k];
                    pz += sWhh[(10 + f) * 10 + k] * ha[k];
                }
            }
            float vr = -pr * LOG2E + br0[j];
            float vz = -pz * LOG2E + bz0[j];
            v2f ah = {0.f, 0.f};
            #pragma unroll
            for (int i = 0; i < 5; ++i) ah += wnh2[j][i] * h2[i];
            float r = __builtin_amdgcn_rcpf(1.f + __builtin_amdgcn_exp2f(vr));
            float z = __builtin_amdgcn_rcpf(1.f + __builtin_amdgcn_exp2f(vz));
            float y = bni0[j] + r * (ah.x + ah.y + bnh[j]);
            float n = 1.f - 2.f * __builtin_amdgcn_rcpf(1.f + __builtin_amdgcn_exp2f(y));
            hold[j] = n + z * (hold[j] - n);
        }
        GATHER();
        O_AND_STORE();
    }

    // ---- t = 1 .. 511 ----
    #pragma unroll 1
    for (int t = 1; t < STEPS; ++t) {
        #pragma unroll
        for (int j = 0; j < 3; ++j) {
            v2f ar = {0.f, 0.f}, az = {0.f, 0.f}, ai = {0.f, 0.f}, ah = {0.f, 0.f};
            #pragma unroll
            for (int i = 0; i < 5; ++i) {
                ar += wr2[j][i] * h2[i];
                az += wz2[j][i] * h2[i];
                ai += wni2[j][i] * h2[i];
                ah += wnh2[j][i] * h2[i];
            }
            float vr = ar.x + ar.y + br[j];
            float vz = az.x + az.y + bz[j];
            float r = __builtin_amdgcn_rcpf(1.f + __builtin_amdgcn_exp2f(vr));
            float z = __builtin_amdgcn_rcpf(1.f + __builtin_amdgcn_exp2f(vz));
            float y = (ai.x + ai.y + bni[j]) + r * (ah.x + ah.y + bnh[j]);
            float n = 1.f - 2.f * __builtin_amdgcn_rcpf(1.f + __builtin_amdgcn_exp2f(y));
            hold[j] = n + z * (hold[j] - n);
        }
        GATHER();
        O_AND_STORE();
    }
}

extern "C" void kernel_launch(void* const* d_in, const int* in_sizes, int n_in,
                              void* d_out, int out_size, void* d_ws, size_t ws_size,
                              hipStream_t stream) {
    (void)in_sizes; (void)n_in; (void)d_ws; (void)ws_size; (void)out_size;
    dim3 grid(512), block(64);   // 16 batches per wave, 512 waves
    gru_decoder_kernel<<<grid, block, 0, stream>>>(
        (const float*)d_in[0], (const float*)d_in[1], (const float*)d_in[2],
        (const float*)d_in[3], (const float*)d_in[4], (const float*)d_in[5],
        (const float*)d_in[6], (const float*)d_in[7], (const float*)d_in[8],
        (float*)d_out);
}

// Round 6
// 315.276 us; speedup vs baseline: 1.4123x; 1.1423x over previous
//
#include <hip/hip_runtime.h>

#define HID 10
#define STEPS 512

typedef __attribute__((ext_vector_type(2))) float v2f;

// broadcast lane ((lane&0x10)|F) within each 32-lane half -> all lanes of each 16-group
template<int F>
static __device__ __forceinline__ float swz(float v) {
    return __int_as_float(__builtin_amdgcn_ds_swizzle(__float_as_int(v), (F << 5) | 0x10));
}

// Lane-parallel fused GRU decoder, 1 feature per lane, 4 batches per wave.
//   batch = blockIdx*4 + (lane>>4); f = lane&15 (f>=10: zero-padded, stores masked)
// Fused recurrence (x-path folded into gate weights):
//   r,z from (Wgi+Whh); ni from Wgi; nh from Whh. o = l1(h) off-path.
// Per wave-step: 20 pk-fma (rz + ninh dots, bias-initialized) + 10 fma (o-dot)
//   + 6 trans + ~10 glue + 10 ds_swizzle broadcasts + 1 masked store.
// 2048 waves -> 2 waves/SIMD: stalls of one wave hide under the other.
__global__ __launch_bounds__(64, 2) void gru_decoder_kernel(
    const float* __restrict__ hidden, const float* __restrict__ w_ih,
    const float* __restrict__ w_hh, const float* __restrict__ b_ih,
    const float* __restrict__ b_hh, const float* __restrict__ l1_w,
    const float* __restrict__ l1_b, const float* __restrict__ l2_w,
    const float* __restrict__ l2_b, float* __restrict__ out)
{
    __shared__ float sWx[640];   // l2_w @ l1_w (64x10)
    __shared__ float sbx[64];    // l2_w @ l1_b + l2_b
    __shared__ float sWgi[300];  // w_ih @ Wx (30x10)
    __shared__ float sbgi[30];   // b_ih + w_ih @ bx
    __shared__ float sWhh[300];  // w_hh copy (t=0 peel)

    const int lane = threadIdx.x;
    const int f    = lane & 15;
    const int b    = blockIdx.x * 4 + (lane >> 4);
    const bool ok  = (f < HID);
    const int fi   = ok ? f : 0;          // clamped index for safe reads

    // ---- preamble: fused weights (fp32, cooperative) ----
    for (int e = lane; e < 640; e += 64) {
        int i = e / 10, j = e - i * 10;
        float acc = 0.f;
        #pragma unroll
        for (int k = 0; k < 10; ++k) acc += l2_w[i * 10 + k] * l1_w[k * 10 + j];
        sWx[e] = acc;
    }
    {
        float acc = l2_b[lane];
        #pragma unroll
        for (int k = 0; k < 10; ++k) acc += l2_w[lane * 10 + k] * l1_b[k];
        sbx[lane] = acc;
    }
    for (int e = lane; e < 300; e += 64) sWhh[e] = w_hh[e];
    __syncthreads();
    for (int e = lane; e < 300; e += 64) {
        int m = e / 10, j = e - m * 10;
        float acc = 0.f;
        for (int k = 0; k < 64; ++k) acc += w_ih[m * 64 + k] * sWx[k * 10 + j];
        sWgi[e] = acc;
    }
    if (lane < 30) {
        float acc = b_ih[lane];
        for (int k = 0; k < 64; ++k) acc += w_ih[lane * 64 + k] * sbx[k];
        sbgi[lane] = acc;
    }
    __syncthreads();

    const float LOG2E = 1.4426950408889634f;
    const float S2    = 2.f * LOG2E;

    // ---- per-lane weights (feature fi), prefolded scales/negation ----
    v2f wrz[10], wnn[10];
    float wo[10];
    #pragma unroll
    for (int k = 0; k < 10; ++k) {
        float grz_r = -(sWgi[fi * 10 + k] + sWhh[fi * 10 + k]) * LOG2E;
        float grz_z = -(sWgi[(10 + fi) * 10 + k] + sWhh[(10 + fi) * 10 + k]) * LOG2E;
        float gni   = sWgi[(20 + fi) * 10 + k] * S2;
        float gnh   = sWhh[(20 + fi) * 10 + k] * S2;
        wrz[k] = ok ? v2f{grz_r, grz_z} : v2f{0.f, 0.f};
        wnn[k] = ok ? v2f{gni, gnh} : v2f{0.f, 0.f};
        wo[k]  = ok ? l1_w[fi * 10 + k] : 0.f;
    }
    const v2f brz = ok ? v2f{-(sbgi[fi] + b_hh[fi]) * LOG2E,
                             -(sbgi[10 + fi] + b_hh[10 + fi]) * LOG2E}
                       : v2f{0.f, 0.f};
    const v2f bnn = ok ? v2f{sbgi[20 + fi] * S2, b_hh[20 + fi] * S2} : v2f{0.f, 0.f};
    const float bo = ok ? l1_b[fi] : 0.f;
    // t=0 peel biases (gi = b_ih only)
    const v2f brz0 = ok ? v2f{-(b_ih[fi] + b_hh[fi]) * LOG2E,
                              -(b_ih[10 + fi] + b_hh[10 + fi]) * LOG2E}
                        : v2f{0.f, 0.f};
    const float bni0 = ok ? b_ih[20 + fi] * S2 : 0.f;

    // ---- initial h (one feature per lane; f>=10 stays exactly 0) ----
    float h = ok ? hidden[(size_t)b * HID + f] : 0.f;

    float ha[10];
    #define GATHER()                                                       \
        ha[0] = swz<0>(h); ha[1] = swz<1>(h); ha[2] = swz<2>(h);           \
        ha[3] = swz<3>(h); ha[4] = swz<4>(h); ha[5] = swz<5>(h);           \
        ha[6] = swz<6>(h); ha[7] = swz<7>(h); ha[8] = swz<8>(h);           \
        ha[9] = swz<9>(h);

    GATHER();

    float* pb = out + (size_t)b * (STEPS * HID) + (size_t)(STEPS - 1) * HID + f;

    #define O_AND_STORE()                                                  \
        {                                                                  \
            float o = bo;                                                  \
            _Pragma("unroll")                                              \
            for (int k = 0; k < 10; ++k) o += wo[k] * ha[k];               \
            if (ok) pb[0] = o;                                             \
            pb -= HID;                                                     \
        }

    // ---- t = 0 peeled: gi = b_ih only (x_0 = 0); raw w_hh dots from LDS ----
    {
        float pr = 0.f, pz = 0.f, ph = 0.f;
        #pragma unroll
        for (int k = 0; k < 10; ++k) {
            pr += sWhh[fi * 10 + k] * ha[k];
            pz += sWhh[(10 + fi) * 10 + k] * ha[k];
            ph += sWhh[(20 + fi) * 10 + k] * ha[k];
        }
        float vr = brz0.x - pr * LOG2E;
        float vz = brz0.y - pz * LOG2E;
        float r = __builtin_amdgcn_rcpf(1.f + __builtin_amdgcn_exp2f(vr));
        float z = __builtin_amdgcn_rcpf(1.f + __builtin_amdgcn_exp2f(vz));
        float y = bni0 + r * (ph * S2 + bnn.y);
        float n = 1.f - 2.f * __builtin_amdgcn_rcpf(1.f + __builtin_amdgcn_exp2f(y));
        h = ok ? (n + z * (h - n)) : 0.f;
        GATHER();
        O_AND_STORE();
    }

    // ---- t = 1 .. 511 ----
    #pragma unroll 1
    for (int t = 1; t < STEPS; ++t) {
        v2f arz = brz, ann = bnn;
        #pragma unroll
        for (int k = 0; k < 10; ++k) {
            v2f hh = {ha[k], ha[k]};
            arz += wrz[k] * hh;
            ann += wnn[k] * hh;
        }
        float r = __builtin_amdgcn_rcpf(1.f + __builtin_amdgcn_exp2f(arz.x));
        float z = __builtin_amdgcn_rcpf(1.f + __builtin_amdgcn_exp2f(arz.y));
        float y = ann.x + r * ann.y;
        float n = 1.f - 2.f * __builtin_amdgcn_rcpf(1.f + __builtin_amdgcn_exp2f(y));
        h = n + z * (h - n);          // f>=10: all-zero weights/biases keep h == 0
        GATHER();
        O_AND_STORE();
    }
}

extern "C" void kernel_launch(void* const* d_in, const int* in_sizes, int n_in,
                              void* d_out, int out_size, void* d_ws, size_t ws_size,
                              hipStream_t stream) {
    (void)in_sizes; (void)n_in; (void)d_ws; (void)ws_size; (void)out_size;
    dim3 grid(2048), block(64);   // 4 batches/wave, 2048 waves -> 2 waves per SIMD
    gru_decoder_kernel<<<grid, block, 0, stream>>>(
        (const float*)d_in[0], (const float*)d_in[1], (const float*)d_in[2],
        (const float*)d_in[3], (const float*)d_in[4], (const float*)d_in[5],
        (const float*)d_in[6], (const float*)d_in[7], (const float*)d_in[8],
        (float*)d_out);
}